// Round 1
// baseline (514.180 us; speedup 1.0000x reference)
//
#include <hip/hip_runtime.h>
#include <hip/hip_bf16.h>
#include <hip/hip_fp16.h>

typedef unsigned short u16;
typedef __attribute__((ext_vector_type(8))) short short8;
typedef __attribute__((ext_vector_type(4))) float floatx4;

#define N_TOK 4096
#define D_DIM 256
#define H_HEAD 8

__device__ __forceinline__ u16 f2b(float f){
  __hip_bfloat16 h = __float2bfloat16(f);
  return *reinterpret_cast<u16*>(&h);
}

__device__ __forceinline__ void glds16(const void* g, void* l){
  __builtin_amdgcn_global_load_lds(
      (const __attribute__((address_space(1))) unsigned int*)g,
      (__attribute__((address_space(3))) unsigned int*)l, 16, 0, 0);
}

// ---------------- fp32 -> bf16 convert ----------------
__global__ void cvt_f32_bf16(const float* __restrict__ src, u16* __restrict__ dst, int n){
  int i = (blockIdx.x*256 + threadIdx.x)*8;
  if (i >= n) return;
  float4 a = *(const float4*)(src + i);
  float4 b = *(const float4*)(src + i + 4);
  u16 u[8] = {f2b(a.x),f2b(a.y),f2b(a.z),f2b(a.w),f2b(b.x),f2b(b.y),f2b(b.z),f2b(b.w)};
  *(short8*)(dst + i) = *(short8*)u;
}

// ---------------- layernorm: fp32 in -> bf16 out ----------------
__global__ void ln_kernel(const float* __restrict__ x, const float* __restrict__ g,
                          const float* __restrict__ b, u16* __restrict__ out){
  const int row = blockIdx.x;
  const int t = threadIdx.x;
  float v = x[(size_t)row*D_DIM + t];
  float s = v, ss = v*v;
  #pragma unroll
  for (int off = 32; off > 0; off >>= 1){
    s  += __shfl_down(s,  off);
    ss += __shfl_down(ss, off);
  }
  __shared__ float ls[4], lss[4];
  const int w = t >> 6, lane = t & 63;
  if (lane == 0){ ls[w] = s; lss[w] = ss; }
  __syncthreads();
  if (t == 0){
    float S  = ls[0]+ls[1]+ls[2]+ls[3];
    float SS = lss[0]+lss[1]+lss[2]+lss[3];
    float mu = S * (1.0f/D_DIM);
    float var = SS * (1.0f/D_DIM) - mu*mu;
    ls[0] = mu; lss[0] = rsqrtf(var + 1e-5f);
  }
  __syncthreads();
  float mu = ls[0], rs = lss[0];
  out[(size_t)row*D_DIM + t] = f2b((v - mu)*rs*g[t] + b[t]);
}

// ---------------- bias16: combined spatial+edge+mask, fp16 ----------------
__global__ void make_bias(const float* __restrict__ sp, const float* __restrict__ ed,
                          const int* __restrict__ mask, __half* __restrict__ out){
  const int row = blockIdx.y;
  const int col = (blockIdx.x*256 + threadIdx.x)*4;
  const int mr = mask[row];
  float4 s = *(const float4*)(sp + (size_t)row*N_TOK + col);
  float4 e = *(const float4*)(ed + (size_t)row*N_TOK + col);
  int4  mc = *(const int4*)(mask + col);
  float v0 = (mr*mc.x)==0 ? -30000.f : s.x + e.x;
  float v1 = (mr*mc.y)==0 ? -30000.f : s.y + e.y;
  float v2 = (mr*mc.z)==0 ? -30000.f : s.z + e.z;
  float v3 = (mr*mc.w)==0 ? -30000.f : s.w + e.w;
  __half2* o2 = (__half2*)(out + (size_t)row*N_TOK + col);
  o2[0] = __halves2half2(__float2half(v0), __float2half(v1));
  o2[1] = __halves2half2(__float2half(v2), __float2half(v3));
}

// ---------------- V transpose: [h][n][e] -> [h][e][n], bf16 ----------------
__global__ void transpose_v(const u16* __restrict__ v, u16* __restrict__ vt){
  __shared__ u16 t[64][72];
  const int h = blockIdx.z;
  const int n0 = blockIdx.x*64, e0 = blockIdx.y*64;
  const int tid = threadIdx.x;
  const int r = tid >> 2;
  const int c = (tid & 3)*16;
  const u16* src = v + ((size_t)h*N_TOK + n0 + r)*D_DIM + e0 + c;
  short8 a = *(const short8*)src;
  short8 b = *(const short8*)(src + 8);
  #pragma unroll
  for (int i = 0; i < 8; ++i){ t[r][c+i] = ((u16*)&a)[i]; t[r][c+8+i] = ((u16*)&b)[i]; }
  __syncthreads();
  u16 tmp[16];
  #pragma unroll
  for (int i = 0; i < 16; ++i) tmp[i] = t[c+i][r];
  u16* dst = vt + ((size_t)h*D_DIM + e0 + r)*N_TOK + n0 + c;
  *(short8*)dst       = *(short8*)tmp;
  *(short8*)(dst + 8) = *(short8*)(tmp + 8);
}

// ---------------- bf16 GEMM, C = A * B^T (+bias, +resid) ----------------
// A: [M, K] bf16 row-major, B: [Ncols, K] bf16 row-major.
// MODE 0: QKV — out bf16, addr = (col>>8)*N*D + row*256 + (col&255), bias fp32.
// MODE 1/2: out fp32 = acc + bias[col] + resid[row*256+col].
template<int BM, int BN, int MODE>
__launch_bounds__(256, 2)
__global__ void gemm_bt(const u16* __restrict__ A, const u16* __restrict__ B, int K,
                        const float* __restrict__ bias, const float* __restrict__ resid,
                        void* __restrict__ Cout){
  constexpr int BK = 32;
  constexpr int WM = BM/2, WN = BN/2, FM = WM/16, FN = WN/16;
  constexpr int CApW = BM/64;   // 1024B chunks (16 rows) per wave
  constexpr int CBpW = BN/64;
  __shared__ u16 As[BM*BK];
  __shared__ u16 Bs[BN*BK];
  const int tid = threadIdx.x, w = tid>>6, lane = tid&63;
  const int quad = lane>>4, c16 = lane&15;
  const int wr = w>>1, wc = w&1;
  const int rowT = blockIdx.y*BM, colT = blockIdx.x*BN;
  const int lr = lane>>2;         // row within 16-row chunk
  const int sp = lane&3;          // slot position within row (4 x 16B)

  floatx4 acc[FM][FN] = {};

  for (int k0 = 0; k0 < K; k0 += BK){
    #pragma unroll
    for (int i = 0; i < CApW; ++i){
      int ch = w*CApW + i;
      int row = ch*16 + lr;
      int gch = sp ^ ((row>>1)&3);               // swizzled global chunk
      const u16* g = A + (size_t)(rowT + row)*K + k0 + gch*8;
      glds16(g, As + ch*512);
    }
    #pragma unroll
    for (int i = 0; i < CBpW; ++i){
      int ch = w*CBpW + i;
      int row = ch*16 + lr;
      int gch = sp ^ ((row>>1)&3);
      const u16* g = B + (size_t)(colT + row)*K + k0 + gch*8;
      glds16(g, Bs + ch*512);
    }
    __syncthreads();
    short8 af[FM], bf[FN];
    #pragma unroll
    for (int i = 0; i < FM; ++i){
      int row = wr*WM + i*16 + c16;
      int slot = quad ^ ((row>>1)&3);
      af[i] = *(const short8*)&As[row*BK + slot*8];
    }
    #pragma unroll
    for (int j = 0; j < FN; ++j){
      int row = wc*WN + j*16 + c16;
      int slot = quad ^ ((row>>1)&3);
      bf[j] = *(const short8*)&Bs[row*BK + slot*8];
    }
    #pragma unroll
    for (int i = 0; i < FM; ++i)
      #pragma unroll
      for (int j = 0; j < FN; ++j)
        acc[i][j] = __builtin_amdgcn_mfma_f32_16x16x32_bf16(af[i], bf[j], acc[i][j], 0, 0, 0);
    __syncthreads();
  }

  if (MODE == 0){
    u16* o = (u16*)Cout;
    #pragma unroll
    for (int i = 0; i < FM; ++i)
      #pragma unroll
      for (int j = 0; j < FN; ++j){
        int col = colT + wc*WN + j*16 + c16;
        float bv = bias[col];
        size_t obase = (size_t)(col>>8)*((size_t)N_TOK*D_DIM) + (col & 255);
        #pragma unroll
        for (int r = 0; r < 4; ++r){
          int row = rowT + wr*WM + i*16 + quad*4 + r;
          o[obase + (size_t)row*D_DIM] = f2b(acc[i][j][r] + bv);
        }
      }
  } else {
    float* o = (float*)Cout;
    #pragma unroll
    for (int i = 0; i < FM; ++i)
      #pragma unroll
      for (int j = 0; j < FN; ++j){
        int col = colT + wc*WN + j*16 + c16;
        float bv = bias[col];
        #pragma unroll
        for (int r = 0; r < 4; ++r){
          int row = rowT + wr*WM + i*16 + quad*4 + r;
          size_t idx = (size_t)row*D_DIM + col;
          o[idx] = acc[i][j][r] + bv + resid[idx];
        }
      }
  }
}

// ---------------- flash attention ----------------
// Q,K: [h][n][e] bf16; Vt: [h][e][n] bf16; bias: [n][m] fp16; cat out: [n][h*256+e] bf16.
// Block: 64 q-rows, head = blockIdx.y. Wave w owns q rows [w*16, w*16+16).
__launch_bounds__(256, 2)
__global__ void attn_kernel(const u16* __restrict__ Q, const u16* __restrict__ Kg,
                            const u16* __restrict__ Vt, const __half* __restrict__ bias,
                            u16* __restrict__ cat){
  extern __shared__ __align__(16) u16 lds[];
  u16* Ks = lds;                 // [64][256], chunk-swizzled
  u16* Vs = lds + 64*256;        // [256][64], chunk-swizzled
  u16* Ps = lds + 64*256 + 256*64; // [4 waves][16][64], chunk-swizzled
  const int h = blockIdx.y, q0 = blockIdx.x*64;
  const int tid = threadIdx.x, w = tid>>6, lane = tid&63;
  const int quad = lane>>4, c16 = lane&15;
  const size_t hoff = (size_t)h*N_TOK*D_DIM;

  // Q fragments in registers (A-operand): m = c16 row, k = ks*32 + quad*8 + j
  short8 qf[8];
  {
    const u16* qp = Q + hoff + (size_t)(q0 + w*16 + c16)*D_DIM + quad*8;
    #pragma unroll
    for (int ks = 0; ks < 8; ++ks) qf[ks] = *(const short8*)(qp + ks*32);
  }

  floatx4 o[16] = {};
  float m_i[4] = {-3e38f,-3e38f,-3e38f,-3e38f};
  float l_i[4] = {0.f,0.f,0.f,0.f};

  const u16* Kb = Kg + hoff;
  const u16* Vb = Vt + (size_t)h*D_DIM*N_TOK;
  const int krow = lane>>5;        // K staging: 2 rows per 1024B chunk
  const int ksp  = lane&31;        // slot position (32 x 16B per row)
  const int vrow = lane>>3;        // V staging: 8 rows per chunk
  const int vsp  = lane&7;         // slot position (8 x 16B per row)

  for (int t = 0; t < 64; ++t){
    // ---- stage K tile [64][256] and Vt tile [256][64], swizzled ----
    #pragma unroll
    for (int i = 0; i < 8; ++i){
      int ch = w*8 + i;
      {
        int row = ch*2 + krow;
        int gch = ksp ^ (row&7);
        const u16* g = Kb + (size_t)(t*64 + row)*D_DIM + gch*8;
        glds16(g, Ks + ch*512);
      }
      {
        int e = ch*8 + vrow;
        int gch = vsp ^ (e&7);
        const u16* g = Vb + (size_t)e*N_TOK + t*64 + gch*8;
        glds16(g, Vs + ch*512);
      }
    }
    __syncthreads();

    // ---- S = Q K^T ----
    floatx4 s4[4] = {};
    #pragma unroll
    for (int nb = 0; nb < 4; ++nb){
      int row = nb*16 + c16;
      #pragma unroll
      for (int ks = 0; ks < 8; ++ks){
        int slot = (ks*4 + quad) ^ (row&7);
        short8 bfr = *(const short8*)&Ks[row*256 + slot*8];
        s4[nb] = __builtin_amdgcn_mfma_f32_16x16x32_bf16(qf[ks], bfr, s4[nb], 0, 0, 0);
      }
    }

    // ---- online softmax (fp32) ----
    float sv[4][4], vmax[4] = {-3e38f,-3e38f,-3e38f,-3e38f};
    const __half* bp = bias + (size_t)(q0 + w*16 + quad*4)*N_TOK + t*64 + c16;
    #pragma unroll
    for (int r = 0; r < 4; ++r){
      #pragma unroll
      for (int nb = 0; nb < 4; ++nb){
        float bv = __half2float(bp[(size_t)r*N_TOK + nb*16]);
        float s = s4[nb][r]*0.0625f + bv;
        sv[r][nb] = s;
        vmax[r] = fmaxf(vmax[r], s);
      }
    }
    #pragma unroll
    for (int r = 0; r < 4; ++r){
      float v = vmax[r];
      v = fmaxf(v, __shfl_xor(v, 1, 16));
      v = fmaxf(v, __shfl_xor(v, 2, 16));
      v = fmaxf(v, __shfl_xor(v, 4, 16));
      v = fmaxf(v, __shfl_xor(v, 8, 16));
      vmax[r] = v;
    }
    float alpha[4], p[4][4];
    #pragma unroll
    for (int r = 0; r < 4; ++r){
      float mn = fmaxf(m_i[r], vmax[r]);
      alpha[r] = __expf(m_i[r] - mn);
      m_i[r] = mn;
      float su = 0.f;
      #pragma unroll
      for (int nb = 0; nb < 4; ++nb){
        float pp = __expf(sv[r][nb] - mn);
        p[r][nb] = pp; su += pp;
      }
      su += __shfl_xor(su, 1, 16);
      su += __shfl_xor(su, 2, 16);
      su += __shfl_xor(su, 4, 16);
      su += __shfl_xor(su, 8, 16);
      l_i[r] = l_i[r]*alpha[r] + su;
    }
    // rescale O
    #pragma unroll
    for (int eb = 0; eb < 16; ++eb){
      floatx4 t4 = o[eb];
      t4[0] *= alpha[0]; t4[1] *= alpha[1]; t4[2] *= alpha[2]; t4[3] *= alpha[3];
      o[eb] = t4;
    }
    // ---- P -> LDS (bf16), swizzled ----
    u16* Pw = Ps + w*1024;
    #pragma unroll
    for (int r = 0; r < 4; ++r){
      int m = quad*4 + r;
      #pragma unroll
      for (int nb = 0; nb < 4; ++nb){
        int cidx = nb*2 + (c16>>3);
        int slot = cidx ^ (m&7);
        Pw[m*64 + slot*8 + (c16&7)] = f2b(p[r][nb]);
      }
    }
    // ---- O += P V ----
    #pragma unroll
    for (int ks2 = 0; ks2 < 2; ++ks2){
      int pslot = (ks2*4 + quad) ^ (c16&7);
      short8 pf = *(const short8*)&Pw[c16*64 + pslot*8];
      #pragma unroll
      for (int eb = 0; eb < 16; ++eb){
        int e = eb*16 + c16;
        int slot = (ks2*4 + quad) ^ (e&7);
        short8 vf = *(const short8*)&Vs[e*64 + slot*8];
        o[eb] = __builtin_amdgcn_mfma_f32_16x16x32_bf16(pf, vf, o[eb], 0, 0, 0);
      }
    }
    __syncthreads();
  }

  // ---- epilogue ----
  float inv[4];
  #pragma unroll
  for (int r = 0; r < 4; ++r)
    inv[r] = (m_i[r] > -20000.f && l_i[r] > 0.f) ? 1.0f/l_i[r] : 0.f;
  u16* cp = cat + (size_t)(q0 + w*16 + quad*4)*(H_HEAD*D_DIM) + h*D_DIM + c16;
  #pragma unroll
  for (int eb = 0; eb < 16; ++eb)
    #pragma unroll
    for (int r = 0; r < 4; ++r)
      cp[(size_t)r*(H_HEAD*D_DIM) + eb*16] = f2b(o[eb][r]*inv[r]);
}

// ---------------- launch ----------------
extern "C" void kernel_launch(void* const* d_in, const int* in_sizes, int n_in,
                              void* d_out, int out_size, void* d_ws, size_t ws_size,
                              hipStream_t stream){
  const float* x    = (const float*)d_in[0];
  const int*   mask = (const int*)  d_in[1];
  const float* sp   = (const float*)d_in[2];
  const float* ed   = (const float*)d_in[3];
  const float* g1   = (const float*)d_in[4];
  const float* b1   = (const float*)d_in[5];
  const float* Wq   = (const float*)d_in[6];
  const float* bq   = (const float*)d_in[7];
  const float* Wk   = (const float*)d_in[8];
  const float* bk   = (const float*)d_in[9];
  const float* Wv   = (const float*)d_in[10];
  const float* bv   = (const float*)d_in[11];
  const float* Wo   = (const float*)d_in[12];
  const float* bo   = (const float*)d_in[13];
  const float* g2   = (const float*)d_in[14];
  const float* b2   = (const float*)d_in[15];
  const float* Wff  = (const float*)d_in[16];
  const float* bff  = (const float*)d_in[17];
  float* out = (float*)d_out;
  char* ws = (char*)d_ws;

  constexpr size_t MB = 1ull<<20;
  u16*    xln    = (u16*)   (ws + 0);        // 2 MB
  u16*    wqkv   = (u16*)   (ws + 2*MB);     // 3 MB
  u16*    wo_b   = (u16*)   (ws + 5*MB);     // 1 MB
  u16*    wff_b  = (u16*)   (ws + 6*MB);     // 128 KB
  float*  bqkv   = (float*) (ws + 6*MB + 512*1024); // 24 KB
  u16*    qkv    = (u16*)   (ws + 7*MB);     // 48 MB (q,k,v each 16 MB)
  u16*    vt     = (u16*)   (ws + 55*MB);    // 16 MB
  __half* bias16 = (__half*)(ws + 71*MB);    // 32 MB
  u16*    cat    = (u16*)   (ws + 103*MB);   // 16 MB
  float*  xout   = (float*) (ws + 119*MB);   // 4 MB
  u16*    xln2   = (u16*)   (ws + 123*MB);   // 2 MB
  const size_t TS = (size_t)H_HEAD*N_TOK*D_DIM; // 8388608 elements per tensor

  // weight conversions
  cvt_f32_bf16<<<256, 256, 0, stream>>>(Wq, wqkv, 524288);
  cvt_f32_bf16<<<256, 256, 0, stream>>>(Wk, wqkv + 524288, 524288);
  cvt_f32_bf16<<<256, 256, 0, stream>>>(Wv, wqkv + 1048576, 524288);
  cvt_f32_bf16<<<256, 256, 0, stream>>>(Wo, wo_b, 524288);
  cvt_f32_bf16<<<32,  256, 0, stream>>>(Wff, wff_b, 65536);
  hipMemcpyAsync(bqkv,        bq, 2048*sizeof(float), hipMemcpyDeviceToDevice, stream);
  hipMemcpyAsync(bqkv + 2048, bk, 2048*sizeof(float), hipMemcpyDeviceToDevice, stream);
  hipMemcpyAsync(bqkv + 4096, bv, 2048*sizeof(float), hipMemcpyDeviceToDevice, stream);

  // LN1
  ln_kernel<<<N_TOK, 256, 0, stream>>>(x, g1, b1, xln);

  // QKV projection: [4096,256] x [6144,256]^T
  gemm_bt<128,128,0><<<dim3(48, 32), 256, 0, stream>>>(xln, wqkv, 256, bqkv, nullptr, qkv);

  // V transpose
  transpose_v<<<dim3(64, 4, 8), 256, 0, stream>>>(qkv + 2*TS, vt);

  // combined bias (spatial + edge + mask) as fp16
  make_bias<<<dim3(4, N_TOK), 256, 0, stream>>>(sp, ed, mask, bias16);

  // flash attention
  hipFuncSetAttribute((const void*)attn_kernel,
                      hipFuncAttributeMaxDynamicSharedMemorySize, 73728);
  attn_kernel<<<dim3(64, 8), 256, 73728, stream>>>(qkv, qkv + TS, vt, bias16, cat);

  // output projection + residual: [4096,2048] x [256,2048]^T + bo + x
  gemm_bt<64,64,1><<<dim3(4, 64), 256, 0, stream>>>(cat, wo_b, 2048, bo, x, xout);

  // LN2
  ln_kernel<<<N_TOK, 256, 0, stream>>>(xout, g2, b2, xln2);

  // FF + residual: [4096,256] x [256,256]^T + bff + xout
  gemm_bt<64,64,2><<<dim3(4, 64), 256, 0, stream>>>(xln2, wff_b, 256, bff, xout, out);
}